// Round 10
// baseline (179.674 us; speedup 1.0000x reference)
//
#include <hip/hip_runtime.h>
#include <math.h>

// MultiHeadAttention: B=2, T=2048, C=1024, H=16, D=64, causal, fp32 in/out.
// R21: attn v16 = QBLK 128 (was 64), KVBLK=64 unchanged. Rationale: the ONLY
// out-of-noise result in 6 rounds was R16, where DOUBLING per-q K/V staging
// cost +17.4us -> staging is the proven sensitivity (~17us of attn's ~40).
// v16 halves it: 4 waves each own a private 32-q band and consume ALL 64
// keys per staged tile (2 ladders/tile, v13's verified kg indexing) ->
// K/V staged once per 128q (avg 17 tiles/block vs 33), and the kh-combine
// disappears (O/lsum wave-local; each wave writes its own rows).
// Block order pairs heavy+light per CU: s = (g<8)?15-g:g-8 -> constant
// 260 ladders/CU. qkv (packed-A) / gemm_out / cvt unchanged from R20.

#define BLOCK 256

typedef __attribute__((ext_vector_type(8))) short bf16x8;
typedef __attribute__((ext_vector_type(4))) float f32x4;
typedef __attribute__((ext_vector_type(16))) float f32x16;

__device__ inline short f2bf(float f) {
  union { float f; unsigned u; } c; c.f = f;
  unsigned u = c.u;
  unsigned r = (u + 0x7fffu + ((u >> 16) & 1u)) >> 16;  // RNE
  return (short)r;
}

// ---------------- fused conversion kernel ----------------
// z = 0..3: W transpose (Wq/Wk/Wv/Wo -> [n][k] bf16).
// z = 4: x -> PACKED-FRAGMENT bf16: offset(row,k) =
//   (row>>4)*16384 + (k>>6)*1024 + ((k>>3)&7)*128 + (row&15)*8 + (k&7).

__global__ void cvt_all_kernel(const float* __restrict__ x,
                               const float* __restrict__ Wq, const float* __restrict__ Wk,
                               const float* __restrict__ Wv, const float* __restrict__ Wo,
                               short* __restrict__ xb,
                               short* __restrict__ Wtqkv, short* __restrict__ Wto) {
  __shared__ float tile[32][33];
  __shared__ __align__(16) short xtile[4096];  // [c8l 0..31][slot 0..15][8]
  int z = blockIdx.z;
  if (z >= 4) {  // x packing: 1024 blocks, each = (row-tile rt, k-quarter sq)
    int blk = blockIdx.x + (blockIdx.y << 5);  // 0..1023
    int rt = blk >> 2, sq = blk & 3;
    int row_l = threadIdx.x >> 4, q = threadIdx.x & 15;
    const float* xr = x + (size_t)(rt * 16 + row_l) * 1024 + sq * 256 + q * 16;
    float4 f0 = *(const float4*)(xr);
    float4 f1 = *(const float4*)(xr + 4);
    float4 f2 = *(const float4*)(xr + 8);
    float4 f3 = *(const float4*)(xr + 12);
    alignas(16) short e0[8], e1[8];
    e0[0] = f2bf(f0.x); e0[1] = f2bf(f0.y); e0[2] = f2bf(f0.z); e0[3] = f2bf(f0.w);
    e0[4] = f2bf(f1.x); e0[5] = f2bf(f1.y); e0[6] = f2bf(f1.z); e0[7] = f2bf(f1.w);
    e1[0] = f2bf(f2.x); e1[1] = f2bf(f2.y); e1[2] = f2bf(f2.z); e1[3] = f2bf(f2.w);
    e1[4] = f2bf(f3.x); e1[5] = f2bf(f3.y); e1[6] = f2bf(f3.z); e1[7] = f2bf(f3.w);
    int c0 = q * 2, c1 = q * 2 + 1;  // local 8-elem chunk index (k>>3 within 256)
    *(int4*)&xtile[(c0 * 16 + (row_l ^ (c0 & 15))) * 8] = *(const int4*)e0;
    *(int4*)&xtile[(c1 * 16 + (row_l ^ (c1 & 15))) * 8] = *(const int4*)e1;
    __syncthreads();
    int lc = threadIdx.x & 15, c8x = threadIdx.x >> 4;
#pragma unroll
    for (int hh = 0; hh < 2; hh++) {
      int c8l = c8x + hh * 16;
      int4 v = *(const int4*)&xtile[(c8l * 16 + (lc ^ (c8l & 15))) * 8];
      int s = sq * 4 + (c8l >> 3), c8 = c8l & 7;
      *(int4*)&xb[(size_t)rt * 16384 + s * 1024 + c8 * 128 + lc * 8] = v;
    }
    return;
  }
  const float* W = (z == 0) ? Wq : (z == 1) ? Wk : (z == 2) ? Wv : Wo;
  short* outp = (z == 3) ? Wto : (Wtqkv + (size_t)z * 1024 * 1024);
  int k0 = blockIdx.x * 32, n0 = blockIdx.y * 32;
  int tr = threadIdx.x >> 5, tc = threadIdx.x & 31;
#pragma unroll
  for (int i = 0; i < 4; i++)
    tile[tr + i * 8][tc] = W[(k0 + tr + i * 8) * 1024 + n0 + tc];
  __syncthreads();
#pragma unroll
  for (int i = 0; i < 4; i++)
    outp[(n0 + tr + i * 8) * 1024 + k0 + tc] = f2bf(tile[tc][tr + i * 8]);
}

// ---------------- fused QKV GEMM (A direct-packed, B reg-staged) ----------

__global__ __launch_bounds__(BLOCK, 3) void gemm_qkv_kernel(
    const short* __restrict__ A, const short* __restrict__ Wt,
    const float* __restrict__ bq, const float* __restrict__ bk,
    const float* __restrict__ bv,
    short* __restrict__ Qo, short* __restrict__ Ko, short* __restrict__ Vo) {
  const int Kd = 1024;
  const float QSCL = 0.18033688011f;  // 0.125 * log2(e)
  int p = blockIdx.x;
  int xcd = p & 7, j = p >> 3;  // j: 0..95 within the XCD
  int m0 = ((xcd & 3) * 8 + (j & 7)) * 128;
  int n0 = ((xcd >> 2) * 12 + (j >> 3)) * 128;
  int t = threadIdx.x;
  int lane = t & 63, wv = t >> 6;
  int quad = lane >> 4, lc = lane & 15;
  int wy = wv >> 1, wx = wv & 1;
  __shared__ short Bs[128 * 64];  // [row][slot^swz], 16KB (B only)
  f32x4 acc[4][4] = {};

  int sr = wv * 32 + (lane >> 3);  // B staging base row
  int schk = lane & 7;             // linear global 16B chunk
  const short* Bb = Wt + (size_t)(n0 + sr) * Kd + schk * 8;
  int wslot = schk ^ (lane >> 3);  // swizzled LDS write slot
  short* wb = &Bs[sr * 64 + wslot * 8];
  const short* Ap = A + (size_t)m0 * 1024;
  int abase = wy * 4 * 16384 + lane * 8;

  bf16x8 sB[4];
#pragma unroll
  for (int i = 0; i < 4; i++)
    sB[i] = *(const bf16x8*)(Bb + (size_t)(i * 8) * Kd);

  int rx = lc & 7;  // B reader xor (row&7 == lc&7)
  for (int step = 0; step < 16; step++) {
#pragma unroll
    for (int i = 0; i < 4; i++)
      *(bf16x8*)(wb + i * 8 * 64) = sB[i];
    asm volatile("s_waitcnt lgkmcnt(0)" ::: "memory");  // writes landed
    __builtin_amdgcn_s_barrier();                       // tile visible
    asm volatile("" ::: "memory");
    // A fragments for this step: 8 coalesced global b128 (L2 hits)
    bf16x8 af2[2][4];
#pragma unroll
    for (int kc2 = 0; kc2 < 2; kc2++)
#pragma unroll
      for (int i = 0; i < 4; i++)
        af2[kc2][i] = *(const bf16x8*)(Ap + (size_t)abase + i * 16384 +
                                       step * 1024 + kc2 * 512);
    if (step + 1 < 16) {  // prefetch next B tile; wait is next ds_write
      int koff = (step + 1) * 64;
#pragma unroll
      for (int i = 0; i < 4; i++)
        sB[i] = *(const bf16x8*)(Bb + (size_t)(i * 8) * Kd + koff);
    }
#pragma unroll
    for (int kc = 0; kc < 2; kc++) {
      bf16x8 bf[4];
#pragma unroll
      for (int i = 0; i < 4; i++)
        bf[i] = *(const bf16x8*)&Bs[(wx * 64 + i * 16 + lc) * 64 +
                                    ((kc * 4 + quad) ^ rx) * 8];
#pragma unroll
      for (int mi = 0; mi < 4; mi++)
#pragma unroll
        for (int ni = 0; ni < 4; ni++)
          acc[mi][ni] = __builtin_amdgcn_mfma_f32_16x16x32_bf16(af2[kc][mi], bf[ni], acc[mi][ni], 0, 0, 0);
    }
    asm volatile("s_waitcnt lgkmcnt(0)" ::: "memory");  // B reads drained
    __builtin_amdgcn_s_barrier();                       // before overwrite
    asm volatile("" ::: "memory");
  }
#pragma unroll
  for (int mi = 0; mi < 4; mi++) {
    int row = m0 + wy * 64 + mi * 16 + quad * 4;
#pragma unroll
    for (int ni = 0; ni < 4; ni++) {
      int col = n0 + wx * 64 + ni * 16 + lc;
      int which = col >> 10;  // block-uniform (n-tile never straddles 1024)
      int hd = col & 1023;
      int h = hd >> 6, d = hd & 63;
      float bb = (which == 0) ? bq[hd] : (which == 1) ? bk[hd] : bv[hd];
      if (which == 2) {  // V^T [b,h,d,t], pack 4 consecutive t
        alignas(8) short pk[4];
#pragma unroll
        for (int r = 0; r < 4; r++) pk[r] = f2bf(acc[mi][ni][r] + bb);
        int b = row >> 11, tt = row & 2047;
        *(int2*)&Vo[((size_t)(b * 16 + h) * 64 + d) * 2048 + tt] = *(const int2*)pk;
      } else {
#pragma unroll
        for (int r = 0; r < 4; r++) {
          int rw = row + r;
          int b = rw >> 11, tt = rw & 2047;
          float val = acc[mi][ni][r] + bb;
          if (which == 0) {
            Qo[((size_t)(b * 16 + h) * 2048 + tt) * 64 + d] = f2bf(val * QSCL);
          } else {
            Ko[((size_t)(b * 16 + h) * 2048 + tt) * 64 + d] = f2bf(val);
          }
        }
      }
    }
  }
}

// ---------------- out-projection GEMM (reg-staged, BK=64) ----------------
// R14 version verbatim. 64x128 tile, grid (64,8).

__global__ __launch_bounds__(BLOCK) void gemm_out_kernel(
    const short* __restrict__ A, const short* __restrict__ Wt,
    const float* __restrict__ bias, float* __restrict__ Out) {
  const int Kd = 1024;
  int m0 = blockIdx.x * 64, n0 = blockIdx.y * 128;
  int t = threadIdx.x;
  int lane = t & 63, wv = t >> 6;
  int quad = lane >> 4, lc = lane & 15;
  int wy = wv >> 1, wx = wv & 1;
  __shared__ short As[64 * 64];   // 8KB, [row][slot^swz]
  __shared__ short Bs[128 * 64];  // 16KB
  f32x4 acc[2][4] = {};

  int lr = lane >> 3;
  int schk = lane & 7;
  int wslot = schk ^ lr;
  int srA = wv * 16 + lr;
  int srB = wv * 32 + lr;
  const short* Ab = A + (size_t)(m0 + srA) * Kd + schk * 8;
  const short* Bb = Wt + (size_t)(n0 + srB) * Kd + schk * 8;
  short* wa = &As[srA * 64 + wslot * 8];
  short* wb = &Bs[srB * 64 + wslot * 8];

  bf16x8 sA[2], sB[4];
#pragma unroll
  for (int i = 0; i < 2; i++) sA[i] = *(const bf16x8*)(Ab + (size_t)(i * 8) * Kd);
#pragma unroll
  for (int i = 0; i < 4; i++) sB[i] = *(const bf16x8*)(Bb + (size_t)(i * 8) * Kd);

  int rx = lc & 7;
  for (int step = 0; step < 16; step++) {
#pragma unroll
    for (int i = 0; i < 2; i++) *(bf16x8*)(wa + i * 8 * 64) = sA[i];
#pragma unroll
    for (int i = 0; i < 4; i++) *(bf16x8*)(wb + i * 8 * 64) = sB[i];
    asm volatile("s_waitcnt lgkmcnt(0)" ::: "memory");
    __builtin_amdgcn_s_barrier();
    asm volatile("" ::: "memory");
    if (step + 1 < 16) {
      int koff = (step + 1) * 64;
#pragma unroll
      for (int i = 0; i < 2; i++)
        sA[i] = *(const bf16x8*)(Ab + (size_t)(i * 8) * Kd + koff);
#pragma unroll
      for (int i = 0; i < 4; i++)
        sB[i] = *(const bf16x8*)(Bb + (size_t)(i * 8) * Kd + koff);
    }
#pragma unroll
    for (int kc = 0; kc < 2; kc++) {
      bf16x8 af[2], bf[4];
#pragma unroll
      for (int i = 0; i < 2; i++)
        af[i] = *(const bf16x8*)&As[(wy * 32 + i * 16 + lc) * 64 +
                                    ((kc * 4 + quad) ^ rx) * 8];
#pragma unroll
      for (int i = 0; i < 4; i++)
        bf[i] = *(const bf16x8*)&Bs[(wx * 64 + i * 16 + lc) * 64 +
                                    ((kc * 4 + quad) ^ rx) * 8];
#pragma unroll
      for (int mi = 0; mi < 2; mi++)
#pragma unroll
        for (int ni = 0; ni < 4; ni++)
          acc[mi][ni] = __builtin_amdgcn_mfma_f32_16x16x32_bf16(af[mi], bf[ni], acc[mi][ni], 0, 0, 0);
    }
    asm volatile("s_waitcnt lgkmcnt(0)" ::: "memory");
    __builtin_amdgcn_s_barrier();
    asm volatile("" ::: "memory");
  }
#pragma unroll
  for (int mi = 0; mi < 2; mi++) {
    int row = m0 + wy * 32 + mi * 16 + quad * 4;
#pragma unroll
    for (int ni = 0; ni < 4; ni++) {
      int col = n0 + wx * 64 + ni * 16 + lc;
      float bb = bias[col];
#pragma unroll
      for (int r = 0; r < 4; r++)
        Out[(size_t)(row + r) * 1024 + col] = acc[mi][ni][r] + bb;
    }
  }
}

// ---------------- flash attention v16 (QBLK=128, wave-private q bands) ----
// Grid 512 = 32 bh x 16 strips of 128 q. Block order: g = p>>5, s = (g<8)?
// 15-g : g-8 (co-resident pairs sum to uniform CU load). Wave w owns q rows
// [s*128 + w*32, +32) and consumes ALL 64 keys of each staged KVBLK=64 tile
// (2 ladders/tile, kg loop). K/V staged once per 128 q (half of v12's
// traffic); no kh-combine (O/lsum wave-local; each wave writes its rows).
// Reg-staged single-buffer pipeline, xor-swizzled LDS, fixed-max softmax.

__global__ __launch_bounds__(BLOCK, 2) void attn_kernel(
    const short* __restrict__ Q, const short* __restrict__ K,
    const short* __restrict__ Vt, short* __restrict__ Oa) {
  int p = blockIdx.x;
  int bh = ((p & 7) << 2) | ((p >> 3) & 3);  // same bh -> same XCD (p%8)
  int g = p >> 5;                            // 0..15
  int s = (g < 8) ? (15 - g) : (g - 8);      // heavy blocks dispatch first
  int t = threadIdx.x;
  int lane = t & 63, w = t >> 6;             // wave = private 32-q band
  int ln = lane & 31, lh = lane >> 5;
  const short* Qb = Q + (size_t)bh * 2048 * 64;
  const short* Kb = K + (size_t)bh * 2048 * 64;
  const short* Vg = Vt + (size_t)bh * 64 * 2048;
  int b = bh >> 4, h = bh & 15;

  __shared__ short Kt[64 * 64];  // [key][chunk-swizzled d], stride 64
  __shared__ short Vs[64 * 64];  // [d][chunk-swizzled key], stride 64
  __shared__ __align__(16) short Ps[4][32 * 72];  // per-wave P (64 keys/row)
  short* Pw = Ps[w];

  int srow = t >> 3;                    // staging row sub-index 0..31
  int schk = t & 7;                     // linear global 16B chunk
  int wslot = (schk ^ (srow & 7)) * 8;  // swizzled LDS slot
  const float M2 = 14.5f;               // fixed softmax max, log2 domain
  int xk = ln & 7;                      // reader xor (row&7)

  int q0w = s * 128 + w * 32;  // this wave's q band
  int qmaxw = q0w + 31;
  int ntiles = 2 * (s + 1);    // keys 0 .. 128(s+1)

  // Q B-frags (n=q, k=d), 4 chunks of 16 d
  bf16x8 qf[4];
#pragma unroll
  for (int c = 0; c < 4; c++)
    qf[c] = *(const bf16x8*)&Qb[(size_t)(q0w + ln) * 64 + c * 16 + lh * 8];

  f32x16 O0 = {}, O1 = {};
  float lsum = 0.f;

  // prologue: stage tile 0 into regs (linear chunks; swizzle at ds_write)
  bf16x8 sK[2], sV[2];
#pragma unroll
  for (int i = 0; i < 2; i++) {
    int r = i * 32 + srow;
    sK[i] = *(const bf16x8*)&Kb[(size_t)r * 64 + schk * 8];
    sV[i] = *(const bf16x8*)&Vg[(size_t)r * 2048 + schk * 8];
  }
  for (int kt = 0; kt < ntiles; kt++) {
    // ds_write staged tile (compiler-placed vmcnt wait lands here, after
    // the previous tile's full compute phase)
#pragma unroll
    for (int i = 0; i < 2; i++) {
      int r = i * 32 + srow;
      *(bf16x8*)&Kt[r * 64 + wslot] = sK[i];
      *(bf16x8*)&Vs[r * 64 + wslot] = sV[i];
    }
    asm volatile("s_waitcnt lgkmcnt(0)" ::: "memory");  // writes landed
    __builtin_amdgcn_s_barrier();                       // tile visible
    asm volatile("" ::: "memory");
    if (kt + 1 < ntiles) {  // issue next-tile loads -> regs
      int kb2 = (kt + 1) * 64;
#pragma unroll
      for (int i = 0; i < 2; i++) {
        int r = i * 32 + srow;
        sK[i] = *(const bf16x8*)&Kb[(size_t)(kb2 + r) * 64 + schk * 8];
        sV[i] = *(const bf16x8*)&Vg[(size_t)r * 2048 + kb2 + schk * 8];
      }
    }
#pragma unroll
    for (int kg = 0; kg < 2; kg++) {
      int grpbase = kt * 64 + kg * 32;  // 32-key group
      if (grpbase <= qmaxw) {           // group intersects this wave's band
        // S^T = K(group) * Q^T : C[m=key32][n=q32]
        f32x16 S = {};
#pragma unroll
        for (int c = 0; c < 4; c++) {
          int ch = c * 2 + lh;  // 16B d-chunk index
          bf16x8 kf = *(const bf16x8*)&Kt[(kg * 32 + ln) * 64 + (ch ^ xk) * 8];
          S = __builtin_amdgcn_mfma_f32_32x32x16_bf16(kf, qf[c], S, 0, 0, 0);
        }
        if (grpbase + 31 > q0w) {  // group crosses this band's diagonal
          int qg = q0w + ln;
#pragma unroll
          for (int reg = 0; reg < 16; reg++) {
            int key = grpbase + (reg & 3) + 8 * (reg >> 2) + 4 * lh;
            if (key > qg) S[reg] = -3.0e38f;
          }
        }
        // p = exp2(s - M2); l-tree; pack 4 keys -> b64
#pragma unroll
        for (int g4 = 0; g4 < 4; g4++) {
          unsigned u[4];
          float e[4];
#pragma unroll
          for (int i = 0; i < 4; i++) {
            union { float f; unsigned v; } cc;
            cc.f = __builtin_amdgcn_exp2f(S[g4 * 4 + i] - M2);
            e[i] = cc.f;
            u[i] = cc.v + 0x8000u;  // round-half-up before truncate
          }
          lsum += (e[0] + e[1]) + (e[2] + e[3]);  // pairwise tree
          int2 pk;
          pk.x = (int)__builtin_amdgcn_perm(u[1], u[0], 0x07060302);
          pk.y = (int)__builtin_amdgcn_perm(u[3], u[2], 0x07060302);
          *(int2*)&Pw[ln * 72 + kg * 32 + g4 * 8 + lh * 4] = pk;
        }
        // PV over this group's 32 keys (per-wave LDS, in-order)
#pragma unroll
        for (int cc = 0; cc < 2; cc++) {
          bf16x8 pf = *(const bf16x8*)&Pw[ln * 72 + kg * 32 + cc * 16 + lh * 8];
          int ch = kg * 4 + cc * 2 + lh;  // 16B key-chunk within tile
          bf16x8 v0 = *(const bf16x8*)&Vs[ln * 64 + (ch ^ xk) * 8];
          bf16x8 v1 = *(const bf16x8*)&Vs[(32 + ln) * 64 + (ch ^ xk) * 8];
          O0 = __builtin_amdgcn_mfma_f32_32x32x16_bf16(v0, pf, O0, 0, 0, 0);
          O1 = __builtin_amdgcn_mfma_f32_32x32x16_bf16(v1, pf, O1, 0, 0, 0);
        }
      }
    }
    asm volatile("s_waitcnt lgkmcnt(0)" ::: "memory");  // reads drained
    __builtin_amdgcn_s_barrier();                       // before next overwrite
    asm volatile("" ::: "memory");
  }

  // ---- epilogue: every wave writes its own 32 q rows (no combine) ----
  float lt = lsum;
  lt += __shfl_xor(lt, 32, 64);  // lanes ln / ln+32 hold same q, split keys
  float inv = 1.0f / lt;
  size_t rowbase = (size_t)(b * 2048 + q0w + ln) * 1024 + h * 64;
#pragma unroll
  for (int dh = 0; dh < 2; dh++)
#pragma unroll
    for (int g4 = 0; g4 < 4; g4++) {
      alignas(8) short pk[4];
#pragma unroll
      for (int i = 0; i < 4; i++) {
        float v = dh ? O1[g4 * 4 + i] : O0[g4 * 4 + i];
        pk[i] = f2bf(v * inv);
      }
      *(int2*)&Oa[rowbase + dh * 32 + g4 * 8 + lh * 4] = *(const int2*)pk;
    }
}

// ---------------- launcher ----------------

extern "C" void kernel_launch(void* const* d_in, const int* in_sizes, int n_in,
                              void* d_out, int out_size, void* d_ws, size_t ws_size,
                              hipStream_t stream) {
  const float* x = (const float*)d_in[0];
  const float* Wq = (const float*)d_in[1];
  const float* bq = (const float*)d_in[2];
  const float* Wk = (const float*)d_in[3];
  const float* bk = (const float*)d_in[4];
  const float* Wv = (const float*)d_in[5];
  const float* bv = (const float*)d_in[6];
  const float* Wo = (const float*)d_in[7];
  const float* bo = (const float*)d_in[8];
  char* ws = (char*)d_ws;
  const size_t MB = 1024 * 1024;
  short* xb = (short*)(ws);               // 8 MiB  packed-fragment x bf16
  short* Wtqkv = (short*)(ws + 8 * MB);   // 6 MiB  [3072][1024] bf16
  short* Wto = (short*)(ws + 14 * MB);    // 2 MiB  [1024][1024] bf16
  short* Qb = (short*)(ws + 17 * MB);     // 8 MiB  [2][16][2048][64] bf16 (prescaled)
  short* Kb = (short*)(ws + 25 * MB);     // 8 MiB  [2][16][2048][64] bf16
  short* Vb = (short*)(ws + 33 * MB);     // 8 MiB  V^T [2][16][64][2048] bf16
  short* Att = (short*)(ws + 41 * MB);    // 8 MiB  [4096][1024] bf16
  float* out = (float*)d_out;

  cvt_all_kernel<<<dim3(32, 32, 5), BLOCK, 0, stream>>>(x, Wq, Wk, Wv, Wo, xb, Wtqkv, Wto);
  gemm_qkv_kernel<<<dim3(768), BLOCK, 0, stream>>>(xb, Wtqkv, bq, bk, bv, Qb, Kb, Vb);
  attn_kernel<<<512, BLOCK, 0, stream>>>(Qb, Kb, Vb, Att);
  gemm_out_kernel<<<dim3(64, 8), BLOCK, 0, stream>>>(Att, Wto, bo, out);
}

// Round 13
// 173.248 us; speedup vs baseline: 1.0371x; 1.0371x over previous
//
#include <hip/hip_runtime.h>
#include <math.h>

// MultiHeadAttention: B=2, T=2048, C=1024, H=16, D=64, causal, fp32 in/out.
// R24 = R23 resubmitted verbatim (rounds 8 and 12 both failed on container
// acquisition, not on the kernel). R23: corrected v_permlane32_swap_b32
// usage. ISA semantics: vdst[32:63] <-> vsrc[0:31] (dst keeps lo, src keeps
// hi) — NOT a full half-swap. Correct build: swap(dst=pk[2c2],
// src=pk[2c2+1]) then fragment = {dst.x, dst.y, src.x, src.y}: words 0/1 =
// lambda0 lanes' pk[2c2+lh], words 2/3 = lambda1 lanes' pk[2c2+lh] —
// bit-identical to v12's LDS read. R22's version had operands reversed +
// output order inverted -> permuted keys -> absmax 4.64.
// qkv (packed-A) / gemm_out / cvt unchanged.

#define BLOCK 256

typedef __attribute__((ext_vector_type(8))) short bf16x8;
typedef __attribute__((ext_vector_type(4))) float f32x4;
typedef __attribute__((ext_vector_type(16))) float f32x16;

__device__ inline short f2bf(float f) {
  union { float f; unsigned u; } c; c.f = f;
  unsigned u = c.u;
  unsigned r = (u + 0x7fffu + ((u >> 16) & 1u)) >> 16;  // RNE
  return (short)r;
}

// ---------------- fused conversion kernel ----------------
// z = 0..3: W transpose (Wq/Wk/Wv/Wo -> [n][k] bf16).
// z = 4: x -> PACKED-FRAGMENT bf16: offset(row,k) =
//   (row>>4)*16384 + (k>>6)*1024 + ((k>>3)&7)*128 + (row&15)*8 + (k&7).

__global__ void cvt_all_kernel(const float* __restrict__ x,
                               const float* __restrict__ Wq, const float* __restrict__ Wk,
                               const float* __restrict__ Wv, const float* __restrict__ Wo,
                               short* __restrict__ xb,
                               short* __restrict__ Wtqkv, short* __restrict__ Wto) {
  __shared__ float tile[32][33];
  __shared__ __align__(16) short xtile[4096];  // [c8l 0..31][slot 0..15][8]
  int z = blockIdx.z;
  if (z >= 4) {  // x packing: 1024 blocks, each = (row-tile rt, k-quarter sq)
    int blk = blockIdx.x + (blockIdx.y << 5);  // 0..1023
    int rt = blk >> 2, sq = blk & 3;
    int row_l = threadIdx.x >> 4, q = threadIdx.x & 15;
    const float* xr = x + (size_t)(rt * 16 + row_l) * 1024 + sq * 256 + q * 16;
    float4 f0 = *(const float4*)(xr);
    float4 f1 = *(const float4*)(xr + 4);
    float4 f2 = *(const float4*)(xr + 8);
    float4 f3 = *(const float4*)(xr + 12);
    alignas(16) short e0[8], e1[8];
    e0[0] = f2bf(f0.x); e0[1] = f2bf(f0.y); e0[2] = f2bf(f0.z); e0[3] = f2bf(f0.w);
    e0[4] = f2bf(f1.x); e0[5] = f2bf(f1.y); e0[6] = f2bf(f1.z); e0[7] = f2bf(f1.w);
    e1[0] = f2bf(f2.x); e1[1] = f2bf(f2.y); e1[2] = f2bf(f2.z); e1[3] = f2bf(f2.w);
    e1[4] = f2bf(f3.x); e1[5] = f2bf(f3.y); e1[6] = f2bf(f3.z); e1[7] = f2bf(f3.w);
    int c0 = q * 2, c1 = q * 2 + 1;  // local 8-elem chunk index (k>>3 within 256)
    *(int4*)&xtile[(c0 * 16 + (row_l ^ (c0 & 15))) * 8] = *(const int4*)e0;
    *(int4*)&xtile[(c1 * 16 + (row_l ^ (c1 & 15))) * 8] = *(const int4*)e1;
    __syncthreads();
    int lc = threadIdx.x & 15, c8x = threadIdx.x >> 4;
#pragma unroll
    for (int hh = 0; hh < 2; hh++) {
      int c8l = c8x + hh * 16;
      int4 v = *(const int4*)&xtile[(c8l * 16 + (lc ^ (c8l & 15))) * 8];
      int s = sq * 4 + (c8l >> 3), c8 = c8l & 7;
      *(int4*)&xb[(size_t)rt * 16384 + s * 1024 + c8 * 128 + lc * 8] = v;
    }
    return;
  }
  const float* W = (z == 0) ? Wq : (z == 1) ? Wk : (z == 2) ? Wv : Wo;
  short* outp = (z == 3) ? Wto : (Wtqkv + (size_t)z * 1024 * 1024);
  int k0 = blockIdx.x * 32, n0 = blockIdx.y * 32;
  int tr = threadIdx.x >> 5, tc = threadIdx.x & 31;
#pragma unroll
  for (int i = 0; i < 4; i++)
    tile[tr + i * 8][tc] = W[(k0 + tr + i * 8) * 1024 + n0 + tc];
  __syncthreads();
#pragma unroll
  for (int i = 0; i < 4; i++)
    outp[(n0 + tr + i * 8) * 1024 + k0 + tc] = f2bf(tile[tc][tr + i * 8]);
}

// ---------------- fused QKV GEMM (A direct-packed, B reg-staged) ----------

__global__ __launch_bounds__(BLOCK, 3) void gemm_qkv_kernel(
    const short* __restrict__ A, const short* __restrict__ Wt,
    const float* __restrict__ bq, const float* __restrict__ bk,
    const float* __restrict__ bv,
    short* __restrict__ Qo, short* __restrict__ Ko, short* __restrict__ Vo) {
  const int Kd = 1024;
  const float QSCL = 0.18033688011f;  // 0.125 * log2(e)
  int p = blockIdx.x;
  int xcd = p & 7, j = p >> 3;  // j: 0..95 within the XCD
  int m0 = ((xcd & 3) * 8 + (j & 7)) * 128;
  int n0 = ((xcd >> 2) * 12 + (j >> 3)) * 128;
  int t = threadIdx.x;
  int lane = t & 63, wv = t >> 6;
  int quad = lane >> 4, lc = lane & 15;
  int wy = wv >> 1, wx = wv & 1;
  __shared__ short Bs[128 * 64];  // [row][slot^swz], 16KB (B only)
  f32x4 acc[4][4] = {};

  int sr = wv * 32 + (lane >> 3);  // B staging base row
  int schk = lane & 7;             // linear global 16B chunk
  const short* Bb = Wt + (size_t)(n0 + sr) * Kd + schk * 8;
  int wslot = schk ^ (lane >> 3);  // swizzled LDS write slot
  short* wb = &Bs[sr * 64 + wslot * 8];
  const short* Ap = A + (size_t)m0 * 1024;
  int abase = wy * 4 * 16384 + lane * 8;

  bf16x8 sB[4];
#pragma unroll
  for (int i = 0; i < 4; i++)
    sB[i] = *(const bf16x8*)(Bb + (size_t)(i * 8) * Kd);

  int rx = lc & 7;  // B reader xor (row&7 == lc&7)
  for (int step = 0; step < 16; step++) {
#pragma unroll
    for (int i = 0; i < 4; i++)
      *(bf16x8*)(wb + i * 8 * 64) = sB[i];
    asm volatile("s_waitcnt lgkmcnt(0)" ::: "memory");  // writes landed
    __builtin_amdgcn_s_barrier();                       // tile visible
    asm volatile("" ::: "memory");
    // A fragments for this step: 8 coalesced global b128 (L2 hits)
    bf16x8 af2[2][4];
#pragma unroll
    for (int kc2 = 0; kc2 < 2; kc2++)
#pragma unroll
      for (int i = 0; i < 4; i++)
        af2[kc2][i] = *(const bf16x8*)(Ap + (size_t)abase + i * 16384 +
                                       step * 1024 + kc2 * 512);
    if (step + 1 < 16) {  // prefetch next B tile; wait is next ds_write
      int koff = (step + 1) * 64;
#pragma unroll
      for (int i = 0; i < 4; i++)
        sB[i] = *(const bf16x8*)(Bb + (size_t)(i * 8) * Kd + koff);
    }
#pragma unroll
    for (int kc = 0; kc < 2; kc++) {
      bf16x8 bf[4];
#pragma unroll
      for (int i = 0; i < 4; i++)
        bf[i] = *(const bf16x8*)&Bs[(wx * 64 + i * 16 + lc) * 64 +
                                    ((kc * 4 + quad) ^ rx) * 8];
#pragma unroll
      for (int mi = 0; mi < 4; mi++)
#pragma unroll
        for (int ni = 0; ni < 4; ni++)
          acc[mi][ni] = __builtin_amdgcn_mfma_f32_16x16x32_bf16(af2[kc][mi], bf[ni], acc[mi][ni], 0, 0, 0);
    }
    asm volatile("s_waitcnt lgkmcnt(0)" ::: "memory");  // B reads drained
    __builtin_amdgcn_s_barrier();                       // before overwrite
    asm volatile("" ::: "memory");
  }
#pragma unroll
  for (int mi = 0; mi < 4; mi++) {
    int row = m0 + wy * 64 + mi * 16 + quad * 4;
#pragma unroll
    for (int ni = 0; ni < 4; ni++) {
      int col = n0 + wx * 64 + ni * 16 + lc;
      int which = col >> 10;  // block-uniform (n-tile never straddles 1024)
      int hd = col & 1023;
      int h = hd >> 6, d = hd & 63;
      float bb = (which == 0) ? bq[hd] : (which == 1) ? bk[hd] : bv[hd];
      if (which == 2) {  // V^T [b,h,d,t], pack 4 consecutive t
        alignas(8) short pk[4];
#pragma unroll
        for (int r = 0; r < 4; r++) pk[r] = f2bf(acc[mi][ni][r] + bb);
        int b = row >> 11, tt = row & 2047;
        *(int2*)&Vo[((size_t)(b * 16 + h) * 64 + d) * 2048 + tt] = *(const int2*)pk;
      } else {
#pragma unroll
        for (int r = 0; r < 4; r++) {
          int rw = row + r;
          int b = rw >> 11, tt = rw & 2047;
          float val = acc[mi][ni][r] + bb;
          if (which == 0) {
            Qo[((size_t)(b * 16 + h) * 2048 + tt) * 64 + d] = f2bf(val * QSCL);
          } else {
            Ko[((size_t)(b * 16 + h) * 2048 + tt) * 64 + d] = f2bf(val);
          }
        }
      }
    }
  }
}

// ---------------- out-projection GEMM (reg-staged, BK=64) ----------------
// R14 version verbatim. 64x128 tile, grid (64,8).

__global__ __launch_bounds__(BLOCK) void gemm_out_kernel(
    const short* __restrict__ A, const short* __restrict__ Wt,
    const float* __restrict__ bias, float* __restrict__ Out) {
  const int Kd = 1024;
  int m0 = blockIdx.x * 64, n0 = blockIdx.y * 128;
  int t = threadIdx.x;
  int lane = t & 63, wv = t >> 6;
  int quad = lane >> 4, lc = lane & 15;
  int wy = wv >> 1, wx = wv & 1;
  __shared__ short As[64 * 64];   // 8KB, [row][slot^swz]
  __shared__ short Bs[128 * 64];  // 16KB
  f32x4 acc[2][4] = {};

  int lr = lane >> 3;
  int schk = lane & 7;
  int wslot = schk ^ lr;
  int srA = wv * 16 + lr;
  int srB = wv * 32 + lr;
  const short* Ab = A + (size_t)(m0 + srA) * Kd + schk * 8;
  const short* Bb = Wt + (size_t)(n0 + srB) * Kd + schk * 8;
  short* wa = &As[srA * 64 + wslot * 8];
  short* wb = &Bs[srB * 64 + wslot * 8];

  bf16x8 sA[2], sB[4];
#pragma unroll
  for (int i = 0; i < 2; i++) sA[i] = *(const bf16x8*)(Ab + (size_t)(i * 8) * Kd);
#pragma unroll
  for (int i = 0; i < 4; i++) sB[i] = *(const bf16x8*)(Bb + (size_t)(i * 8) * Kd);

  int rx = lc & 7;
  for (int step = 0; step < 16; step++) {
#pragma unroll
    for (int i = 0; i < 2; i++) *(bf16x8*)(wa + i * 8 * 64) = sA[i];
#pragma unroll
    for (int i = 0; i < 4; i++) *(bf16x8*)(wb + i * 8 * 64) = sB[i];
    asm volatile("s_waitcnt lgkmcnt(0)" ::: "memory");
    __builtin_amdgcn_s_barrier();
    asm volatile("" ::: "memory");
    if (step + 1 < 16) {
      int koff = (step + 1) * 64;
#pragma unroll
      for (int i = 0; i < 2; i++)
        sA[i] = *(const bf16x8*)(Ab + (size_t)(i * 8) * Kd + koff);
#pragma unroll
      for (int i = 0; i < 4; i++)
        sB[i] = *(const bf16x8*)(Bb + (size_t)(i * 8) * Kd + koff);
    }
#pragma unroll
    for (int kc = 0; kc < 2; kc++) {
      bf16x8 af[2], bf[4];
#pragma unroll
      for (int i = 0; i < 2; i++)
        af[i] = *(const bf16x8*)&As[(wy * 32 + i * 16 + lc) * 64 +
                                    ((kc * 4 + quad) ^ rx) * 8];
#pragma unroll
      for (int i = 0; i < 4; i++)
        bf[i] = *(const bf16x8*)&Bs[(wx * 64 + i * 16 + lc) * 64 +
                                    ((kc * 4 + quad) ^ rx) * 8];
#pragma unroll
      for (int mi = 0; mi < 2; mi++)
#pragma unroll
        for (int ni = 0; ni < 4; ni++)
          acc[mi][ni] = __builtin_amdgcn_mfma_f32_16x16x32_bf16(af[mi], bf[ni], acc[mi][ni], 0, 0, 0);
    }
    asm volatile("s_waitcnt lgkmcnt(0)" ::: "memory");
    __builtin_amdgcn_s_barrier();
    asm volatile("" ::: "memory");
  }
#pragma unroll
  for (int mi = 0; mi < 2; mi++) {
    int row = m0 + wy * 32 + mi * 16 + quad * 4;
#pragma unroll
    for (int ni = 0; ni < 4; ni++) {
      int col = n0 + wx * 64 + ni * 16 + lc;
      float bb = bias[col];
#pragma unroll
      for (int r = 0; r < 4; r++)
        Out[(size_t)(row + r) * 1024 + col] = acc[mi][ni][r] + bb;
    }
  }
}

// ---------------- flash attention v17b (v12 + in-register P exchange) -----
// v12 structure: grid 512 = 32 bh x 16 strip-pairs (s, 31-s) of 64 q;
// 2qh x 2kh waves; KVBLK=64 reg-staged single-buffer pipeline; xor-swizzled
// K/V LDS; fixed-max softmax. P never touches LDS: PV B-fragment built with
// v_permlane32_swap_b32 (vdst[32:63] <-> vsrc[0:31]):
//   a = pk[2c2], b = pk[2c2+1]; swap(a.x,b.x); swap(a.y,b.y);
//   fragment = {a.x, a.y, b.x, b.y}
// word0/1 = lambda0 lanes' pk[2c2+lh], word2/3 = lambda1 lanes' pk[2c2+lh]
// == v12's LDS-read fragment bit-for-bit.

__global__ __launch_bounds__(BLOCK, 2) void attn_kernel(
    const short* __restrict__ Q, const short* __restrict__ K,
    const short* __restrict__ Vt, short* __restrict__ Oa) {
  int p = blockIdx.x;
  int bh = ((p & 7) << 2) | ((p >> 3) & 3);  // same bh -> same XCD (p%8)
  int pair = p >> 5;                         // 0..15
  int t = threadIdx.x;
  int lane = t & 63, w = t >> 6;
  int qh = w & 1, kh = w >> 1;
  int ln = lane & 31, lh = lane >> 5;
  const short* Qb = Q + (size_t)bh * 2048 * 64;
  const short* Kb = K + (size_t)bh * 2048 * 64;
  const short* Vg = Vt + (size_t)bh * 64 * 2048;
  int b = bh >> 4, h = bh & 15;

  __shared__ short Kt[64 * 64];   // [key][chunk-swizzled d], stride 64
  __shared__ short Vs[64 * 64];   // [d][chunk-swizzled key], stride 64
  __shared__ float ob[2][2048];   // [qh] O-combine, 16KB
  __shared__ float lx[2][64];

  int srow = t >> 3;                    // staging row sub-index 0..31
  int schk = t & 7;                     // linear global 16B chunk
  int wslot = (schk ^ (srow & 7)) * 8;  // swizzled LDS slot
  const float M2 = 14.5f;               // fixed softmax max, log2 domain
  int xk = ln & 7;                      // reader xor (row&7)

  for (int sp = 0; sp < 2; sp++) {
    int s = sp ? (31 - pair) : pair;
    int q0 = s * 64;
    int q0w = q0 + qh * 32;
    int qmaxw = q0w + 31;
    int ntiles = s + 1;

    // Q B-frags (n=q, k=d), 4 chunks of 16 d
    bf16x8 qf[4];
#pragma unroll
    for (int c = 0; c < 4; c++)
      qf[c] = *(const bf16x8*)&Qb[(size_t)(q0w + ln) * 64 + c * 16 + lh * 8];

    f32x16 O0 = {}, O1 = {};
    float lsum = 0.f;

    // prologue: stage tile 0 into regs (linear chunks; swizzle at ds_write)
    bf16x8 sK[2], sV[2];
#pragma unroll
    for (int i = 0; i < 2; i++) {
      int r = i * 32 + srow;
      sK[i] = *(const bf16x8*)&Kb[(size_t)r * 64 + schk * 8];
      sV[i] = *(const bf16x8*)&Vg[(size_t)r * 2048 + schk * 8];
    }
    for (int kt = 0; kt < ntiles; kt++) {
      // ds_write staged tile (compiler-placed vmcnt wait lands here, after
      // the previous tile's full compute phase)
#pragma unroll
      for (int i = 0; i < 2; i++) {
        int r = i * 32 + srow;
        *(bf16x8*)&Kt[r * 64 + wslot] = sK[i];
        *(bf16x8*)&Vs[r * 64 + wslot] = sV[i];
      }
      asm volatile("s_waitcnt lgkmcnt(0)" ::: "memory");  // writes landed
      __builtin_amdgcn_s_barrier();                       // tile visible
      asm volatile("" ::: "memory");
      if (kt + 1 < ntiles) {  // issue next-tile loads -> regs
        int kb2 = (kt + 1) * 64;
#pragma unroll
        for (int i = 0; i < 2; i++) {
          int r = i * 32 + srow;
          sK[i] = *(const bf16x8*)&Kb[(size_t)(kb2 + r) * 64 + schk * 8];
          sV[i] = *(const bf16x8*)&Vg[(size_t)r * 2048 + kb2 + schk * 8];
        }
      }
      int grpbase = kt * 64 + kh * 32;  // wave-uniform 32-key group
      if (grpbase <= qmaxw) {           // wave active on this tile
        // S^T = K(group) * Q^T : C[m=key32][n=q32]
        f32x16 S = {};
#pragma unroll
        for (int c = 0; c < 4; c++) {
          int ch = c * 2 + lh;  // 16B d-chunk index
          bf16x8 kf = *(const bf16x8*)&Kt[(kh * 32 + ln) * 64 + (ch ^ xk) * 8];
          S = __builtin_amdgcn_mfma_f32_32x32x16_bf16(kf, qf[c], S, 0, 0, 0);
        }
        if (kt == ntiles - 1) {  // diagonal tile: mask key > q
          int qg = q0w + ln;
#pragma unroll
          for (int reg = 0; reg < 16; reg++) {
            int key = grpbase + (reg & 3) + 8 * (reg >> 2) + 4 * lh;
            if (key > qg) S[reg] = -3.0e38f;
          }
        }
        // p = exp2(s - M2); accumulate l; pack 4 keys -> int2 REGS (no LDS)
        int2 pk[4];
#pragma unroll
        for (int g = 0; g < 4; g++) {
          unsigned u[4];
#pragma unroll
          for (int i = 0; i < 4; i++) {
            union { float f; unsigned v; } cc;
            cc.f = __builtin_amdgcn_exp2f(S[g * 4 + i] - M2);
            lsum += cc.f;
            u[i] = cc.v + 0x8000u;  // round-half-up before truncate
          }
          pk[g].x = (int)__builtin_amdgcn_perm(u[1], u[0], 0x07060302);
          pk[g].y = (int)__builtin_amdgcn_perm(u[3], u[2], 0x07060302);
        }
        // PV: build B-fragment in-register. swap semantics:
        // dst[32:63] <-> src[0:31]; dst=pk[2c2], src=pk[2c2+1];
        // fragment = {dst.x, dst.y, src.x, src.y}.
#pragma unroll
        for (int c2 = 0; c2 < 2; c2++) {
          unsigned ax = (unsigned)pk[2 * c2].x, bx = (unsigned)pk[2 * c2 + 1].x;
          unsigned ay = (unsigned)pk[2 * c2].y, by = (unsigned)pk[2 * c2 + 1].y;
          asm volatile("v_permlane32_swap_b32 %0, %1" : "+v"(ax), "+v"(bx));
          asm volatile("v_permlane32_swap_b32 %0, %1" : "+v"(ay), "+v"(by));
          union { unsigned u[4]; bf16x8 v; } pf;
          pf.u[0] = ax; pf.u[1] = ay; pf.u[2] = bx; pf.u[3] = by;
          int ch = kh * 4 + c2 * 2 + lh;  // 16B key-chunk within tile
          bf16x8 v0 = *(const bf16x8*)&Vs[ln * 64 + (ch ^ xk) * 8];
          bf16x8 v1 = *(const bf16x8*)&Vs[(32 + ln) * 64 + (ch ^ xk) * 8];
          O0 = __builtin_amdgcn_mfma_f32_32x32x16_bf16(v0, pf.v, O0, 0, 0, 0);
          O1 = __builtin_amdgcn_mfma_f32_32x32x16_bf16(v1, pf.v, O1, 0, 0, 0);
        }
      }
      asm volatile("s_waitcnt lgkmcnt(0)" ::: "memory");  // reads drained
      __builtin_amdgcn_s_barrier();                       // before next overwrite
      asm volatile("" ::: "memory");
    }

    // ---- combine keyhalf partials through dedicated ob buffer ----
    if (kh == 1) {
      float* obw = ob[qh];
#pragma unroll
      for (int dh = 0; dh < 2; dh++)
#pragma unroll
        for (int reg = 0; reg < 16; reg++)
          obw[((dh * 16 + reg) * 2 + lh) * 32 + ln] = dh ? O1[reg] : O0[reg];
      lx[qh][lane] = lsum;
    }
    __syncthreads();
    if (kh == 0) {
      float* obw = ob[qh];
#pragma unroll
      for (int reg = 0; reg < 16; reg++) {
        O0[reg] += obw[((0 * 16 + reg) * 2 + lh) * 32 + ln];
        O1[reg] += obw[((1 * 16 + reg) * 2 + lh) * 32 + ln];
      }
      float lt = lsum + lx[qh][lane];
      lt += __shfl_xor(lt, 32, 64);
      float inv = 1.0f / lt;
      size_t rowbase = (size_t)(b * 2048 + q0w + ln) * 1024 + h * 64;
#pragma unroll
      for (int dh = 0; dh < 2; dh++)
#pragma unroll
        for (int g = 0; g < 4; g++) {
          alignas(8) short pko[4];
#pragma unroll
          for (int i = 0; i < 4; i++) {
            float v = dh ? O1[g * 4 + i] : O0[g * 4 + i];
            pko[i] = f2bf(v * inv);
          }
          *(int2*)&Oa[rowbase + dh * 32 + g * 8 + lh * 4] = *(const int2*)pko;
        }
    }
    // next strip's tile-loop barriers order ob/lx reuse (kh1 can only reach
    // its next ob write after passing barriers that kh0 passes post-read)
  }
}

// ---------------- launcher ----------------

extern "C" void kernel_launch(void* const* d_in, const int* in_sizes, int n_in,
                              void* d_out, int out_size, void* d_ws, size_t ws_size,
                              hipStream_t stream) {
  const float* x = (const float*)d_in[0];
  const float* Wq = (const float*)d_in[1];
  const float* bq = (const float*)d_in[2];
  const float* Wk = (const float*)d_in[3];
  const float* bk = (const float*)d_in[4];
  const float* Wv = (const float*)d_in[5];
  const float* bv = (const float*)d_in[6];
  const float* Wo = (const float*)d_in[7];
  const float* bo = (const float*)d_in[8];
  char* ws = (char*)d_ws;
  const size_t MB = 1024 * 1024;
  short* xb = (short*)(ws);               // 8 MiB  packed-fragment x bf16
  short* Wtqkv = (short*)(ws + 8 * MB);   // 6 MiB  [3072][1024] bf16
  short* Wto = (short*)(ws + 14 * MB);    // 2 MiB  [1024][1024] bf16
  short* Qb = (short*)(ws + 17 * MB);     // 8 MiB  [2][16][2048][64] bf16 (prescaled)
  short* Kb = (short*)(ws + 25 * MB);     // 8 MiB  [2][16][2048][64] bf16
  short* Vb = (short*)(ws + 33 * MB);     // 8 MiB  V^T [2][16][64][2048] bf16
  short* Att = (short*)(ws + 41 * MB);    // 8 MiB  [4096][1024] bf16
  float* out = (float*)d_out;

  cvt_all_kernel<<<dim3(32, 32, 5), BLOCK, 0, stream>>>(x, Wq, Wk, Wv, Wo, xb, Wtqkv, Wto);
  gemm_qkv_kernel<<<dim3(768), BLOCK, 0, stream>>>(xb, Wtqkv, bq, bk, bv, Qb, Kb, Vb);
  attn_kernel<<<512, BLOCK, 0, stream>>>(Qb, Kb, Vb, Att);
  gemm_out_kernel<<<dim3(64, 8), BLOCK, 0, stream>>>(Att, Wto, bo, out);
}